// Round 2
// baseline (182.802 us; speedup 1.0000x reference)
//
#include <hip/hip_runtime.h>
#include <hip/hip_bf16.h>
#include <stdint.h>

// Problem constants (fixed by setup_inputs)
#define PRIME 2147483647u
#define GAMMA 0.3f
#define K_HASH 128
#define S_SET 8
#define NB 4
#define LQ 1024
#define LK 1024
#define EDIM 512

typedef __attribute__((ext_vector_type(8))) short short8;
typedef __attribute__((ext_vector_type(4))) float f32x4;

static __device__ __forceinline__ unsigned short f2bf(float f) {
    unsigned u = __builtin_bit_cast(unsigned, f);
    u += 0x7FFFu + ((u >> 16) & 1u);   // RNE (no NaN in this problem)
    return (unsigned short)(u >> 16);
}

// ---------------------------------------------------------------------------
// 1) MinHash signatures: sig[b,l,k] = min_s (a[k]*id + b[k]) mod (2^31-1)
//    Mersenne-prime fold instead of 64-bit modulo. int64 inputs arrive as i32.
// ---------------------------------------------------------------------------
__global__ __launch_bounds__(128) void sig_kernel(
        const int* __restrict__ ts_q, const int* __restrict__ ts_k,
        const int* __restrict__ ha, const int* __restrict__ hb,
        int* __restrict__ sig_q, int* __restrict__ sig_k) {
    int blk = blockIdx.x;                 // 0..8191: first 4096 = q sets
    const int* ts = (blk < NB * LQ) ? ts_q : ts_k;
    int*      sig = (blk < NB * LQ) ? sig_q : sig_k;
    int idx = blk & (NB * LQ - 1);
    int k = threadIdx.x;                  // 0..127
    unsigned long long a  = (unsigned)ha[k];
    unsigned long long bb = (unsigned)hb[k];
    __shared__ int ids[S_SET];
    if (k < S_SET) ids[k] = ts[idx * S_SET + k];
    __syncthreads();
    unsigned mn = 0xFFFFFFFFu;
    #pragma unroll
    for (int s = 0; s < S_SET; s++) {
        unsigned long long x = a * (unsigned long long)(unsigned)ids[s] + bb;
        x = (x & PRIME) + (x >> 31);      // 2^31 == 1 (mod 2^31-1)
        x = (x & PRIME) + (x >> 31);
        unsigned r = (unsigned)x;
        if (r >= PRIME) r -= PRIME;
        mn = (r < mn) ? r : mn;
    }
    sig[idx * K_HASH + k] = (int)mn;
}

// ---------------------------------------------------------------------------
// 2) Match counts -> P = exp(score) (bf16), 64x64 tile / block, 4x4 per thread
//    LDS additive swizzle: int4-group g stored at ((g + (row>>2)) & 7) so the
//    stride-4-row reads (kv) spread over all 8 16B bank-groups.
// ---------------------------------------------------------------------------
__global__ __launch_bounds__(256) void jaccard_kernel(
        const int* __restrict__ sig_q, const int* __restrict__ sig_k,
        unsigned short* __restrict__ P) {
    __shared__ int Qs[64 * 32];
    __shared__ int Ks[64 * 32];
    __shared__ float lut[K_HASH + 1];
    int tid = threadIdx.x;
    if (tid <= K_HASH) {
        float r = (float)(K_HASH - tid) / (float)(K_HASH + tid); // (1-J)/(1+J)
        float score = expf(-GAMMA * (2.0f * S_SET) * r);
        lut[tid] = expf(score);           // softmax numerator (scores<=1: no max shift)
    }
    int b  = blockIdx.z;
    int q0 = blockIdx.y * 64, j0 = blockIdx.x * 64;
    const int* sq = sig_q + ((size_t)b * LQ + q0) * K_HASH;
    const int* sk = sig_k + ((size_t)b * LK + j0) * K_HASH;
    int tx = tid & 15, ty = tid >> 4;
    int cnt[4][4] = {};
    int srow = tid >> 2, gbase = (tid & 3) * 2;
    #pragma unroll 1
    for (int ch = 0; ch < 4; ch++) {      // K chunks of 32 hashes
        __syncthreads();
        const int4* gq = (const int4*)(sq + srow * K_HASH + ch * 32);
        const int4* gk = (const int4*)(sk + srow * K_HASH + ch * 32);
        #pragma unroll
        for (int u = 0; u < 2; u++) {
            int g = gbase + u;
            int sg = ((g + (srow >> 2)) & 7) * 4;
            *(int4*)&Qs[srow * 32 + sg] = gq[g];
            *(int4*)&Ks[srow * 32 + sg] = gk[g];
        }
        __syncthreads();
        #pragma unroll
        for (int cc = 0; cc < 8; cc++) {
            int4 qv[4], kv[4];
            #pragma unroll
            for (int i = 0; i < 4; i++) {
                int r = ty * 4 + i;
                qv[i] = *(const int4*)&Qs[r * 32 + (((cc + (r >> 2)) & 7) * 4)];
            }
            #pragma unroll
            for (int j = 0; j < 4; j++) {
                int r = tx * 4 + j;
                kv[j] = *(const int4*)&Ks[r * 32 + (((cc + (r >> 2)) & 7) * 4)];
            }
            #pragma unroll
            for (int i = 0; i < 4; i++)
                #pragma unroll
                for (int j = 0; j < 4; j++)
                    cnt[i][j] += (qv[i].x == kv[j].x) + (qv[i].y == kv[j].y)
                               + (qv[i].z == kv[j].z) + (qv[i].w == kv[j].w);
        }
    }
    unsigned short* Pb = P + (size_t)b * LQ * LK;
    #pragma unroll
    for (int i = 0; i < 4; i++) {
        int q = q0 + ty * 4 + i;
        ushort4 o;
        o.x = f2bf(lut[cnt[i][0]]);
        o.y = f2bf(lut[cnt[i][1]]);
        o.z = f2bf(lut[cnt[i][2]]);
        o.w = f2bf(lut[cnt[i][3]]);
        *(ushort4*)&Pb[(size_t)q * LK + j0 + tx * 4] = o;
    }
}

// ---------------------------------------------------------------------------
// 3) Row sums of P -> 1/sum  (one wave per row)
// ---------------------------------------------------------------------------
__global__ __launch_bounds__(256) void rowsum_kernel(
        const unsigned short* __restrict__ P, float* __restrict__ invs) {
    int wave = threadIdx.x >> 6, lane = threadIdx.x & 63;
    int row = blockIdx.x * 4 + wave;      // 0..B*LQ-1
    const uint4* p4 = (const uint4*)(P + (size_t)row * LK);  // 128 x 16B
    float s = 0.f;
    for (int t = lane; t < LK / 8; t += 64) {
        uint4 v = p4[t];
        unsigned w[4] = {v.x, v.y, v.z, v.w};
        #pragma unroll
        for (int i = 0; i < 4; i++) {
            s += __builtin_bit_cast(float, w[i] << 16);
            s += __builtin_bit_cast(float, w[i] & 0xFFFF0000u);
        }
    }
    #pragma unroll
    for (int off = 32; off > 0; off >>= 1) s += __shfl_down(s, off, 64);
    if (lane == 0) invs[row] = 1.0f / s;
}

// ---------------------------------------------------------------------------
// 4) Generic BT-GEMM: C[M,N] = A[M,K] @ B[N,K]^T (+epilogue), f32 accum via
//    mfma_f32_16x16x32_bf16. 64x64 tile, 4 waves x (32x32).
//    AF32/BF32: global source is f32 -> convert to bf16 while staging to LDS.
//    OUTF32: write f32 (the harness's d_out) instead of bf16 ws tensor.
// ---------------------------------------------------------------------------
#define EPI_ROWBIAS  0
#define EPI_ROWSCALE 1
#define EPI_COLBIAS  2

template<int AF32, int BF32, int OUTF32, int MODE>
__global__ __launch_bounds__(256) void btgemm_kernel(
        const void* __restrict__ Av, const void* __restrict__ Bv,
        void* __restrict__ Cv,
        const float* __restrict__ biasf,   // f32 bias (modes 0,2)
        const float* __restrict__ scalef,  // f32 row scale (mode 1)
        int M, int N, int Kd,
        long long strideA, long long strideB, long long strideC,
        long long strideS) {
    __shared__ unsigned short As[64 * 32];
    __shared__ unsigned short Bs[64 * 32];
    int z = blockIdx.z;
    int m0 = blockIdx.y * 64, n0 = blockIdx.x * 64;
    int tid = threadIdx.x;
    int w = tid >> 6, lane = tid & 63;
    int wm = (w & 1) * 32, wn = (w >> 1) * 32;
    f32x4 acc[2][2] = {};
    int srow = tid >> 2, scol = (tid & 3) * 8;
    const float*          Af = (const float*)Av
                               + (size_t)z * strideA + (size_t)(m0 + srow) * Kd + scol;
    const unsigned short* Ah = (const unsigned short*)Av
                               + (size_t)z * strideA + (size_t)(m0 + srow) * Kd + scol;
    const float*          Bf = (const float*)Bv
                               + (size_t)z * strideB + (size_t)(n0 + srow) * Kd + scol;
    const unsigned short* Bh = (const unsigned short*)Bv
                               + (size_t)z * strideB + (size_t)(n0 + srow) * Kd + scol;
    int mrow = lane & 15, kg = lane >> 4;
    for (int k0 = 0; k0 < Kd; k0 += 32) {
        unsigned short* da = &As[srow * 32 + scol];
        if (AF32) {
            float4 v0 = *(const float4*)(Af + k0);
            float4 v1 = *(const float4*)(Af + k0 + 4);
            da[0] = f2bf(v0.x); da[1] = f2bf(v0.y);
            da[2] = f2bf(v0.z); da[3] = f2bf(v0.w);
            da[4] = f2bf(v1.x); da[5] = f2bf(v1.y);
            da[6] = f2bf(v1.z); da[7] = f2bf(v1.w);
        } else {
            *(uint4*)da = *(const uint4*)(Ah + k0);
        }
        unsigned short* db = &Bs[srow * 32 + scol];
        if (BF32) {
            float4 v0 = *(const float4*)(Bf + k0);
            float4 v1 = *(const float4*)(Bf + k0 + 4);
            db[0] = f2bf(v0.x); db[1] = f2bf(v0.y);
            db[2] = f2bf(v0.z); db[3] = f2bf(v0.w);
            db[4] = f2bf(v1.x); db[5] = f2bf(v1.y);
            db[6] = f2bf(v1.z); db[7] = f2bf(v1.w);
        } else {
            *(uint4*)db = *(const uint4*)(Bh + k0);
        }
        __syncthreads();
        short8 af[2], bfr[2];
        #pragma unroll
        for (int s = 0; s < 2; s++) {
            af[s]  = *(const short8*)&As[(wm + s * 16 + mrow) * 32 + kg * 8];
            bfr[s] = *(const short8*)&Bs[(wn + s * 16 + mrow) * 32 + kg * 8];
        }
        #pragma unroll
        for (int i = 0; i < 2; i++)
            #pragma unroll
            for (int j = 0; j < 2; j++)
                acc[i][j] = __builtin_amdgcn_mfma_f32_16x16x32_bf16(
                                af[i], bfr[j], acc[i][j], 0, 0, 0);
        __syncthreads();
    }
    const float* sc = scalef + (size_t)z * strideS;
    int col = lane & 15, rbase = (lane >> 4) * 4;
    #pragma unroll
    for (int i = 0; i < 2; i++) {
        #pragma unroll
        for (int j = 0; j < 2; j++) {
            #pragma unroll
            for (int r = 0; r < 4; r++) {
                int gm = m0 + wm + i * 16 + rbase + r;
                int gn = n0 + wn + j * 16 + col;
                float v = acc[i][j][r];
                if (MODE == EPI_ROWBIAS)       v += biasf[gm];
                else if (MODE == EPI_ROWSCALE) v *= sc[gm];
                else                           v += biasf[gn];
                size_t cix = (size_t)z * strideC + (size_t)gm * N + gn;
                if (OUTF32) ((float*)Cv)[cix] = v;
                else        ((unsigned short*)Cv)[cix] = f2bf(v);
            }
        }
    }
}

// ---------------------------------------------------------------------------
extern "C" void kernel_launch(void* const* d_in, const int* in_sizes, int n_in,
                              void* d_out, int out_size, void* d_ws, size_t ws_size,
                              hipStream_t stream) {
    // inputs: 0 query 1 key 2 value 3 ts_q 4 ts_k 5 ha 6 hb 7 Wq 8 bq 9 Wk 10 bk
    //         11 Wv 12 bv 13 Wo 14 bo   (q/k projections are dead code:
    //         attention scores come only from the token-set kernel)
    const float* value = (const float*)d_in[2];
    const int* tsq = (const int*)d_in[3];
    const int* tsk = (const int*)d_in[4];
    const int* ha  = (const int*)d_in[5];
    const int* hb  = (const int*)d_in[6];
    const float* Wv = (const float*)d_in[11];
    const float* bv = (const float*)d_in[12];
    const float* Wo = (const float*)d_in[13];
    const float* bo = (const float*)d_in[14];
    float* out = (float*)d_out;

    char* ws = (char*)d_ws;
    int* sigq            = (int*)(ws);                                  // 2 MB
    int* sigk            = (int*)(ws + (2ull << 20));                   // 2 MB
    unsigned short* P    = (unsigned short*)(ws + (4ull << 20));        // 8 MB
    float* invs          = (float*)(ws + (12ull << 20));                // 16 KB
    unsigned short* Vt   = (unsigned short*)(ws + (12ull << 20) + (1ull << 16)); // 4 MB
    unsigned short* ctx  = (unsigned short*)(ws + (17ull << 20));       // 4 MB

    // 1) signatures
    sig_kernel<<<2 * NB * LQ, 128, 0, stream>>>(tsq, tsk, ha, hb, sigq, sigk);

    // 2) P[b,q,j] = exp(score) (bf16)
    jaccard_kernel<<<dim3(LK / 64, LQ / 64, NB), 256, 0, stream>>>(sigq, sigk, P);

    // 3) inverse row sums
    rowsum_kernel<<<NB * LQ / 4, 256, 0, stream>>>(P, invs);

    // 4) Vt[b,d,j] = sum_e Wv[d,e]*value[b,j,e] + bv[d]   (bf16 ws tensor)
    btgemm_kernel<1, 1, 0, EPI_ROWBIAS><<<dim3(LK / 64, EDIM / 64, NB), 256, 0, stream>>>(
        Wv, value, Vt, bv, invs, EDIM, LK, EDIM,
        0LL, (long long)LK * EDIM, (long long)EDIM * LK, 0LL);

    // 5) ctx[b,q,d] = invs[b,q] * sum_j P[b,q,j]*Vt[b,d,j]   (bf16 ws tensor)
    btgemm_kernel<0, 0, 0, EPI_ROWSCALE><<<dim3(EDIM / 64, LQ / 64, NB), 256, 0, stream>>>(
        P, Vt, ctx, bv /*unused*/, invs, LQ, EDIM, LK,
        (long long)LQ * LK, (long long)EDIM * LK, (long long)LQ * EDIM,
        (long long)LQ);

    // 6) out[(b,q),n] = sum_e ctx[b,q,e]*Wo[n,e] + bo[n]   (f32 -> d_out)
    btgemm_kernel<0, 1, 1, EPI_COLBIAS><<<dim3(EDIM / 64, NB * LQ / 64, 1), 256, 0, stream>>>(
        ctx, Wo, out, bo, invs, NB * LQ, EDIM, EDIM,
        0LL, 0LL, 0LL, 0LL);
}

// Round 3
// 179.720 us; speedup vs baseline: 1.0171x; 1.0171x over previous
//
#include <hip/hip_runtime.h>
#include <hip/hip_bf16.h>
#include <stdint.h>

// Problem constants (fixed by setup_inputs)
#define PRIME 2147483647u
#define GAMMA 0.3f
#define K_HASH 128
#define S_SET 8
#define NB 4
#define LQ 1024
#define LK 1024
#define EDIM 512

typedef unsigned short ushort_t;
typedef __attribute__((ext_vector_type(8))) short short8;
typedef __attribute__((ext_vector_type(4))) float f32x4;

static __device__ __forceinline__ unsigned short f2bf(float f) {
    unsigned u = __builtin_bit_cast(unsigned, f);
    u += 0x7FFFu + ((u >> 16) & 1u);   // RNE (no NaN in this problem)
    return (unsigned short)(u >> 16);
}

// async global->LDS, 16B per lane; LDS dst must be lane-contiguous (wave-uniform
// base + lane*16) -- our layouts guarantee it (slot index == tid).
static __device__ __forceinline__ void glds16(const void* g, void* l) {
    __builtin_amdgcn_global_load_lds(
        (const __attribute__((address_space(1))) unsigned int*)g,
        (__attribute__((address_space(3))) unsigned int*)l, 16, 0, 0);
}

// XOR swizzle of 16B chunks within a 64B row: keeps glds lane-contiguous (we
// permute which GLOBAL chunk a lane fetches, same cache line) and makes the
// stride-64B ds_read_b128 fragment reads 2-way/bank (free, m136).
#define SWZ(r) ((((r) >> 2) & 3) ^ ((r) & 3))

// ---------------------------------------------------------------------------
// 0) f32 -> bf16 pre-convert for value / Wv / Wo (one pass, 8 elems/thread)
// ---------------------------------------------------------------------------
#define CVT_N0 (NB * LK * EDIM)          // value: 2,097,152
#define CVT_N1 (EDIM * EDIM)             // Wv:      262,144
#define CVT_N2 (EDIM * EDIM)             // Wo:      262,144
__global__ __launch_bounds__(256) void cvt_kernel(
        const float* __restrict__ v, const float* __restrict__ wv,
        const float* __restrict__ wo,
        ushort_t* __restrict__ vb, ushort_t* __restrict__ wvb,
        ushort_t* __restrict__ wob) {
    size_t i = ((size_t)blockIdx.x * 256 + threadIdx.x) * 8;
    const float* src; ushort_t* dst; size_t off;
    if (i < CVT_N0)                { src = v;  dst = vb;  off = i; }
    else if (i < CVT_N0 + CVT_N1)  { src = wv; dst = wvb; off = i - CVT_N0; }
    else                           { src = wo; dst = wob; off = i - CVT_N0 - CVT_N1; }
    float4 a = *(const float4*)(src + off);
    float4 b = *(const float4*)(src + off + 4);
    ushort4 o0, o1;
    o0.x = f2bf(a.x); o0.y = f2bf(a.y); o0.z = f2bf(a.z); o0.w = f2bf(a.w);
    o1.x = f2bf(b.x); o1.y = f2bf(b.y); o1.z = f2bf(b.z); o1.w = f2bf(b.w);
    *(ushort4*)(dst + off)     = o0;
    *(ushort4*)(dst + off + 4) = o1;
}

// ---------------------------------------------------------------------------
// 1) MinHash signatures (Mersenne-prime fold; int64 ids arrive as i32)
// ---------------------------------------------------------------------------
__global__ __launch_bounds__(128) void sig_kernel(
        const int* __restrict__ ts_q, const int* __restrict__ ts_k,
        const int* __restrict__ ha, const int* __restrict__ hb,
        int* __restrict__ sig_q, int* __restrict__ sig_k) {
    int blk = blockIdx.x;
    const int* ts = (blk < NB * LQ) ? ts_q : ts_k;
    int*      sig = (blk < NB * LQ) ? sig_q : sig_k;
    int idx = blk & (NB * LQ - 1);
    int k = threadIdx.x;
    unsigned long long a  = (unsigned)ha[k];
    unsigned long long bb = (unsigned)hb[k];
    __shared__ int ids[S_SET];
    if (k < S_SET) ids[k] = ts[idx * S_SET + k];
    __syncthreads();
    unsigned mn = 0xFFFFFFFFu;
    #pragma unroll
    for (int s = 0; s < S_SET; s++) {
        unsigned long long x = a * (unsigned long long)(unsigned)ids[s] + bb;
        x = (x & PRIME) + (x >> 31);
        x = (x & PRIME) + (x >> 31);
        unsigned r = (unsigned)x;
        if (r >= PRIME) r -= PRIME;
        mn = (r < mn) ? r : mn;
    }
    sig[idx * K_HASH + k] = (int)mn;
}

// ---------------------------------------------------------------------------
// 2) Match counts -> P = exp(score) (bf16), 64x64 tile, 4x4 per thread
// ---------------------------------------------------------------------------
__global__ __launch_bounds__(256) void jaccard_kernel(
        const int* __restrict__ sig_q, const int* __restrict__ sig_k,
        unsigned short* __restrict__ P) {
    __shared__ int Qs[64 * 32];
    __shared__ int Ks[64 * 32];
    __shared__ float lut[K_HASH + 1];
    int tid = threadIdx.x;
    if (tid <= K_HASH) {
        float r = (float)(K_HASH - tid) / (float)(K_HASH + tid);
        float score = expf(-GAMMA * (2.0f * S_SET) * r);
        lut[tid] = expf(score);           // softmax numerator (scores<=1)
    }
    int b  = blockIdx.z;
    int q0 = blockIdx.y * 64, j0 = blockIdx.x * 64;
    const int* sq = sig_q + ((size_t)b * LQ + q0) * K_HASH;
    const int* sk = sig_k + ((size_t)b * LK + j0) * K_HASH;
    int tx = tid & 15, ty = tid >> 4;
    int cnt[4][4] = {};
    int srow = tid >> 2, gbase = (tid & 3) * 2;
    #pragma unroll 1
    for (int ch = 0; ch < 4; ch++) {
        __syncthreads();
        const int4* gq = (const int4*)(sq + srow * K_HASH + ch * 32);
        const int4* gk = (const int4*)(sk + srow * K_HASH + ch * 32);
        #pragma unroll
        for (int u = 0; u < 2; u++) {
            int g = gbase + u;
            int sg = ((g + (srow >> 2)) & 7) * 4;
            *(int4*)&Qs[srow * 32 + sg] = gq[g];
            *(int4*)&Ks[srow * 32 + sg] = gk[g];
        }
        __syncthreads();
        #pragma unroll
        for (int cc = 0; cc < 8; cc++) {
            int4 qv[4], kv[4];
            #pragma unroll
            for (int i = 0; i < 4; i++) {
                int r = ty * 4 + i;
                qv[i] = *(const int4*)&Qs[r * 32 + (((cc + (r >> 2)) & 7) * 4)];
            }
            #pragma unroll
            for (int j = 0; j < 4; j++) {
                int r = tx * 4 + j;
                kv[j] = *(const int4*)&Ks[r * 32 + (((cc + (r >> 2)) & 7) * 4)];
            }
            #pragma unroll
            for (int i = 0; i < 4; i++)
                #pragma unroll
                for (int j = 0; j < 4; j++)
                    cnt[i][j] += (qv[i].x == kv[j].x) + (qv[i].y == kv[j].y)
                               + (qv[i].z == kv[j].z) + (qv[i].w == kv[j].w);
        }
    }
    unsigned short* Pb = P + (size_t)b * LQ * LK;
    #pragma unroll
    for (int i = 0; i < 4; i++) {
        int q = q0 + ty * 4 + i;
        ushort4 o;
        o.x = f2bf(lut[cnt[i][0]]);
        o.y = f2bf(lut[cnt[i][1]]);
        o.z = f2bf(lut[cnt[i][2]]);
        o.w = f2bf(lut[cnt[i][3]]);
        *(ushort4*)&Pb[(size_t)q * LK + j0 + tx * 4] = o;
    }
}

// ---------------------------------------------------------------------------
// 3) Row sums of P -> 1/sum  (one wave per row)
// ---------------------------------------------------------------------------
__global__ __launch_bounds__(256) void rowsum_kernel(
        const unsigned short* __restrict__ P, float* __restrict__ invs) {
    int wave = threadIdx.x >> 6, lane = threadIdx.x & 63;
    int row = blockIdx.x * 4 + wave;
    const uint4* p4 = (const uint4*)(P + (size_t)row * LK);
    float s = 0.f;
    for (int t = lane; t < LK / 8; t += 64) {
        uint4 v = p4[t];
        unsigned wd[4] = {v.x, v.y, v.z, v.w};
        #pragma unroll
        for (int i = 0; i < 4; i++) {
            s += __builtin_bit_cast(float, wd[i] << 16);
            s += __builtin_bit_cast(float, wd[i] & 0xFFFF0000u);
        }
    }
    #pragma unroll
    for (int off = 32; off > 0; off >>= 1) s += __shfl_down(s, off, 64);
    if (lane == 0) invs[row] = 1.0f / s;
}

// ---------------------------------------------------------------------------
// 4) bf16 BT-GEMM: C[M,N] = A[M,K] @ B[N,K]^T (+epilogue), f32 accum.
//    128x64 tile, 256 thr (4 waves, each 64x32 = 4x2 16x16x32 frags).
//    global_load_lds width-16 staging, XOR-swizzled LDS, double-buffered
//    with ONE barrier per K-step (loads in flight across the MFMA block).
// ---------------------------------------------------------------------------
#define EPI_ROWBIAS  0
#define EPI_ROWSCALE 1
#define EPI_COLBIAS  2

template<int OUTF32, int MODE>
__global__ __launch_bounds__(256) void btgemm_kernel(
        const ushort_t* __restrict__ A, const ushort_t* __restrict__ B,
        void* __restrict__ C,
        const float* __restrict__ bias, const float* __restrict__ scale,
        int lda, int ldb, int ldc, int Kd,
        long long sA, long long sB, long long sC, long long sS) {
    __shared__ ushort_t As[2][128 * 32];   // 8 KB x2
    __shared__ ushort_t Bs[2][64 * 32];    // 4 KB x2
    int z = blockIdx.z;
    int m0 = blockIdx.y * 128, n0 = blockIdx.x * 64;
    int tid = threadIdx.x;
    int w = tid >> 6, lane = tid & 63;
    int wm = (w & 1) * 64, wn = (w >> 1) * 32;
    int mrow = lane & 15, kg = lane >> 4;

    // staging: thread t owns LDS slot t (16B); global chunk swizzled in-row
    int r = tid >> 2, c = (tid & 3) ^ SWZ(r);
    const ushort_t* pa0 = A + (size_t)z * sA + (size_t)(m0 + r) * lda + c * 8;
    const ushort_t* pa1 = pa0 + (size_t)64 * lda;   // rows m0+64..127 (same swz)
    const ushort_t* pb  = B + (size_t)z * sB + (size_t)(n0 + r) * ldb + c * 8;

    // loop-invariant fragment LDS offsets (ushort units)
    int aoff[4], boff[2];
    #pragma unroll
    for (int i = 0; i < 4; i++) {
        int R = wm + i * 16 + mrow;
        aoff[i] = R * 32 + (kg ^ SWZ(R)) * 8;
    }
    #pragma unroll
    for (int j = 0; j < 2; j++) {
        int R = wn + j * 16 + mrow;
        boff[j] = R * 32 + (kg ^ SWZ(R)) * 8;
    }

    f32x4 acc[4][2] = {};
    int nK = Kd >> 5;
    glds16(pa0, &As[0][tid * 8]);
    glds16(pa1, &As[0][2048 + tid * 8]);
    glds16(pb,  &Bs[0][tid * 8]);
    for (int i = 0; i < nK; i++) {
        __syncthreads();                  // drains vmcnt: buf[i&1] ready
        int cur = i & 1, nxt = cur ^ 1;
        if (i + 1 < nK) {
            int k0 = (i + 1) << 5;
            glds16(pa0 + k0, &As[nxt][tid * 8]);
            glds16(pa1 + k0, &As[nxt][2048 + tid * 8]);
            glds16(pb  + k0, &Bs[nxt][tid * 8]);
        }
        short8 af[4], bh[2];
        #pragma unroll
        for (int ii = 0; ii < 4; ii++) af[ii] = *(const short8*)&As[cur][aoff[ii]];
        #pragma unroll
        for (int jj = 0; jj < 2; jj++) bh[jj] = *(const short8*)&Bs[cur][boff[jj]];
        #pragma unroll
        for (int ii = 0; ii < 4; ii++)
            #pragma unroll
            for (int jj = 0; jj < 2; jj++)
                acc[ii][jj] = __builtin_amdgcn_mfma_f32_16x16x32_bf16(
                                  af[ii], bh[jj], acc[ii][jj], 0, 0, 0);
    }

    const float* sc = scale + (size_t)z * sS;
    int col = lane & 15, rbase = (lane >> 4) * 4;
    #pragma unroll
    for (int ii = 0; ii < 4; ii++) {
        #pragma unroll
        for (int jj = 0; jj < 2; jj++) {
            #pragma unroll
            for (int rr = 0; rr < 4; rr++) {
                int gm = m0 + wm + ii * 16 + rbase + rr;
                int gn = n0 + wn + jj * 16 + col;
                float v = acc[ii][jj][rr];
                if (MODE == EPI_ROWBIAS)       v += bias[gm];
                else if (MODE == EPI_ROWSCALE) v *= sc[gm];
                else                           v += bias[gn];
                size_t cix = (size_t)z * sC + (size_t)gm * ldc + gn;
                if (OUTF32) ((float*)C)[cix] = v;
                else        ((ushort_t*)C)[cix] = f2bf(v);
            }
        }
    }
}

// ---------------------------------------------------------------------------
extern "C" void kernel_launch(void* const* d_in, const int* in_sizes, int n_in,
                              void* d_out, int out_size, void* d_ws, size_t ws_size,
                              hipStream_t stream) {
    // inputs: 0 query 1 key 2 value 3 ts_q 4 ts_k 5 ha 6 hb 7 Wq 8 bq 9 Wk 10 bk
    //         11 Wv 12 bv 13 Wo 14 bo   (q/k projections are dead code)
    const float* value = (const float*)d_in[2];
    const int* tsq = (const int*)d_in[3];
    const int* tsk = (const int*)d_in[4];
    const int* ha  = (const int*)d_in[5];
    const int* hb  = (const int*)d_in[6];
    const float* Wv = (const float*)d_in[11];
    const float* bv = (const float*)d_in[12];
    const float* Wo = (const float*)d_in[13];
    const float* bo = (const float*)d_in[14];
    float* out = (float*)d_out;

    char* ws = (char*)d_ws;
    int* sigq        = (int*)(ws);                                   // 2 MB
    int* sigk        = (int*)(ws + (2ull << 20));                    // 2 MB
    ushort_t* P      = (ushort_t*)(ws + (4ull << 20));               // 8 MB
    float* invs      = (float*)(ws + (12ull << 20));                 // 16 KB
    ushort_t* Vt     = (ushort_t*)(ws + (12ull << 20) + (1ull << 16)); // 4 MB [512 x 4096]
    ushort_t* ctx    = (ushort_t*)(ws + (17ull << 20));              // 4 MB [4096 x 512]
    ushort_t* Vb     = (ushort_t*)(ws + (21ull << 20));              // 4 MB [4096 x 512]
    ushort_t* Wvb    = (ushort_t*)(ws + (25ull << 20));              // 512 KB
    ushort_t* Wob    = (ushort_t*)(ws + (25ull << 20) + (512ull << 10)); // 512 KB

    // 0) f32 -> bf16 for GEMM operands
    cvt_kernel<<<(CVT_N0 + CVT_N1 + CVT_N2) / (256 * 8), 256, 0, stream>>>(
        value, Wv, Wo, Vb, Wvb, Wob);

    // 1) signatures
    sig_kernel<<<2 * NB * LQ, 128, 0, stream>>>(tsq, tsk, ha, hb, sigq, sigk);

    // 2) P[b,q,j] = exp(score) (bf16)
    jaccard_kernel<<<dim3(LK / 64, LQ / 64, NB), 256, 0, stream>>>(sigq, sigk, P);

    // 3) inverse row sums
    rowsum_kernel<<<NB * LQ / 4, 256, 0, stream>>>(P, invs);

    // 4) Vt[d, b*1024+j] = sum_e Wvb[d,e]*Vb[b*1024+j, e] + bv[d]
    //    merged over batch: M=512, N=4096, K=512 -> 256 blocks
    btgemm_kernel<0, EPI_ROWBIAS><<<dim3(4096 / 64, 512 / 128, 1), 256, 0, stream>>>(
        Wvb, Vb, Vt, bv, invs /*unused*/,
        EDIM, EDIM, NB * LK, EDIM, 0LL, 0LL, 0LL, 0LL);

    // 5) ctx[b*1024+q, d] = invs[b,q] * sum_j P[b,q,j]*Vt[d, b*1024+j]
    //    per-batch: M=1024, N=512, K=1024 -> 256 blocks
    btgemm_kernel<0, EPI_ROWSCALE><<<dim3(EDIM / 64, LQ / 128, NB), 256, 0, stream>>>(
        P, Vt, ctx, bv /*unused*/, invs,
        LK, NB * LK, EDIM, LK,
        (long long)LQ * LK, (long long)LK, (long long)LQ * EDIM, (long long)LQ);

    // 6) out[bq, n] = sum_e ctx[bq,e]*Wob[n,e] + bo[n]  (f32 -> d_out)
    //    M=4096, N=512, K=512 -> 256 blocks
    btgemm_kernel<1, EPI_COLBIAS><<<dim3(EDIM / 64, NB * LQ / 128, 1), 256, 0, stream>>>(
        ctx, Wob, out, bo, invs /*unused*/,
        EDIM, EDIM, EDIM, EDIM, 0LL, 0LL, 0LL, 0LL);
}